// Round 4
// baseline (8443.005 us; speedup 1.0000x reference)
//
#include <hip/hip_runtime.h>

typedef unsigned short u16;
typedef unsigned int   u32;

static __device__ __forceinline__ float sigf (float x){ return 1.0f/(1.0f+__expf(-x)); }
static __device__ __forceinline__ float tanh_(float x){ return 2.0f/(1.0f+__expf(-2.0f*x)) - 1.0f; }

// sizes
#define NM 2730            // 273*10 distinct (t, j=b%10) rows
#define N_O0 878080        // 245*128*28
#define N_O3 978432        // 273*128*28
#define CBMAX 30           // max chains per sync-group

// ---- transpose f32 -> f32: dst[c*rows+r] = src[r*cols+c] ----
__global__ void k_trf(const float* __restrict__ src, float* __restrict__ dst, int rows, int cols){
  int i = blockIdx.x*256 + threadIdx.x;
  if(i >= rows*cols) return;
  int c = i / rows, r = i - c*rows;
  dst[i] = src[r*cols + c];
}

// ---- zero the spin counters (8 u32) ----
__global__ void k_init(u32* __restrict__ cnt){
  if(threadIdx.x < 8) cnt[threadIdx.x] = 0u;
}

// ---- x (128,300) f32 -> xT[t*128+b] f32 ----
__global__ void k_xT(const float* __restrict__ x, float* __restrict__ xT){
  int i = blockIdx.x*256 + threadIdx.x;
  if(i >= 300*128) return;
  int t = i >> 7, b = i & 127;
  xT[i] = x[b*300 + t];
}

// ---- exponential-smoothing scan: 128 threads, one per batch row ----
__global__ void k_es(const float* __restrict__ xT, const float* __restrict__ alpha,
                     const float* __restrict__ gamma, const float* __restrict__ iseas,
                     float* __restrict__ ST, float* __restrict__ lvlT){
  int b = threadIdx.x;
  float a = sigf(alpha[b]);
  float g = sigf(gamma[b]);
  float S0[7];
  #pragma unroll
  for(int i=0;i<7;i++){ S0[i] = __expf(iseas[b*7+i]); ST[i*128+b] = S0[i]; }
  ST[7*128+b] = S0[0];
  float q0=S0[1],q1=S0[2],q2=S0[3],q3=S0[4],q4=S0[5],q5=S0[6],q6=S0[0];
  float lvl = xT[b]/S0[0];
  lvlT[b] = lvl;
  for(int t=1;t<300;t++){
    float xt = xT[t*128+b];
    float s  = q0;
    lvl = a*(xt/s) + (1.0f-a)*lvl;
    float sn = g*(xt/lvl) + (1.0f-g)*s;
    q0=q1;q1=q2;q2=q3;q3=q4;q4=q5;q5=q6;q6=sn;
    lvlT[t*128+b]   = lvl;
    ST[(t+7)*128+b] = sn;
  }
}

// ---- build window_input for the 10 distinct rows: win[(t*10+j)*49 + f] ----
__global__ void k_win(const float* __restrict__ xT, const float* __restrict__ ST,
                      const float* __restrict__ lvlT, const float* __restrict__ cats,
                      const float* __restrict__ mp, float* __restrict__ win){
  int i = blockIdx.x*256 + threadIdx.x;
  if(i >= NM*49) return;
  int f = i % 49;
  int m = i / 49;
  int j = m % 10, t = m / 10;
  float v;
  if(f < 28){
    int c = t + f;
    v = xT[c*128 + j] / ST[c*128 + j] / lvlT[(t+27)*128 + j];
  } else if(f < 48){
    v = cats[j*20 + (f-28)];
  } else {
    v = mp[0];
  }
  win[i] = v;
}

// ---- actual_values (window_output), per real batch row b (f32 out) ----
__global__ void k_wout(const float* __restrict__ xT, const float* __restrict__ ST,
                       const float* __restrict__ lvlT, float* __restrict__ out1){
  int i = blockIdx.x*256 + threadIdx.x;
  if(i >= N_O0) return;
  int o = i % 28;
  int b = (i/28) % 128;
  int t = i/(28*128);
  int c = 28 + t + o;                    // L + t + o  (<= 299)
  out1[i] = xT[c*128+b] / ST[c*128+b] / lvlT[(27+t)*128+b];
}

// ---- batched xz = X @ WihT + b : block = 8 rows x 1024 gates, 256 threads ----
__global__ __launch_bounds__(256) void k_gemm(const float* __restrict__ X,
                                              const float* __restrict__ WT,   // [F][1024] f32
                                              const float* __restrict__ bias, // [1024] f32
                                              float* __restrict__ Z, int F){
  __shared__ float Xs[8][256];
  const int tid = threadIdx.x;
  const int m0 = blockIdx.x*8;
  for(int p=0;p<8;p++){
    int m = m0+p;
    for(int f=tid; f<F; f+=256)
      Xs[p][f] = (m < NM) ? X[m*F+f] : 0.0f;
  }
  __syncthreads();
  float acc0[8], acc1[8], acc2[8], acc3[8];
  {
    float b0 = bias[tid];
    float b1 = bias[tid+256];
    float b2 = bias[tid+512];
    float b3 = bias[tid+768];
    #pragma unroll
    for(int p=0;p<8;p++){ acc0[p]=b0; acc1[p]=b1; acc2[p]=b2; acc3[p]=b3; }
  }
  #pragma unroll 4
  for(int f=0; f<F; f++){
    float w0 = WT[f*1024 + tid      ];
    float w1 = WT[f*1024 + tid+256  ];
    float w2 = WT[f*1024 + tid+512  ];
    float w3 = WT[f*1024 + tid+768  ];
    #pragma unroll
    for(int p=0;p<8;p++){
      float xv = Xs[p][f];
      acc0[p] += w0*xv; acc1[p] += w1*xv; acc2[p] += w2*xv; acc3[p] += w3*xv;
    }
  }
  for(int p=0;p<8;p++){
    int m = m0+p;
    if(m < NM){
      float* zb = Z + m*1024 + tid;
      zb[0]=acc0[p]; zb[256]=acc1[p]; zb[512]=acc2[p]; zb[768]=acc3[p];
    }
  }
}

// ---- LSTM scan v2: register-resident weights, gate-split across 16 WGs ----
// grid = NG*16 WGs of 256 threads. WG (gg,g): sync-group gg (chains
// [gg*CB, gg*CB+CB)), unit slice [g*16, g*16+16).
// wave w = gate w; lane l: u = l&15, kseg = l>>4 (64 k each).
// Each thread holds 64 Whh weights in VGPRs for the whole kernel.
// Per step: h (LDS) -> partial dots -> shfl_xor reduce -> zLDS -> combine
// (c,h update, write Y + h slice to global) -> fence -> spin-barrier.
__global__ __launch_bounds__(256) void k_scan2(
    const float* __restrict__ Z,
    const float* __restrict__ Whh,   // [1024][256] f32, original layout
    float* __restrict__ Y,
    const float* __restrict__ RES,
    float* __restrict__ Hb,          // [2][60][256] f32 exchange buffer
    u32*  __restrict__ cnt,          // per-group spin counter (pre-zeroed)
    int d, int CB, int smax)
{
  __shared__ float hLDS[CBMAX*256];
  __shared__ float zLDS[CBMAX*64];
  __shared__ float cst [CBMAX*16];
  const int tid = threadIdx.x;
  const int g   = blockIdx.x & 15;
  const int gg  = blockIdx.x >> 4;
  const int w   = tid >> 6;             // gate
  const int l   = tid & 63;
  const int u   = l & 15;
  const int ks  = l >> 4;
  u32* mycnt = cnt + gg;

  // load my 64 weights: row = w*256 + g*16 + u, k = ks*64 + [0,64)
  float wv[64];
  {
    const float4* wr = (const float4*)(Whh + (size_t)(w*256 + g*16 + u)*256 + ks*64);
    #pragma unroll
    for(int i=0;i<16;i++){
      float4 t4 = wr[i];
      wv[4*i]=t4.x; wv[4*i+1]=t4.y; wv[4*i+2]=t4.z; wv[4*i+3]=t4.w;
    }
  }
  for(int i=tid;i<CB*16;i+=256) cst[i]=0.f;
  __syncthreads();

  for(int s=0;s<smax;s++){
    // 1. stage h into LDS (h0 = 0)
    if(s==0){
      for(int i=tid;i<CB*64;i+=256) ((float4*)hLDS)[i]=make_float4(0.f,0.f,0.f,0.f);
    } else {
      const float4* src = (const float4*)(Hb + (size_t)(s&1)*60*256 + (size_t)gg*CB*256);
      for(int i=tid;i<CB*64;i+=256) ((float4*)hLDS)[i]=src[i];
    }
    __syncthreads();
    // 2. partial dots + reduce
    for(int cl=0; cl<CB; cl++){
      int cg = gg*CB + cl;
      int r  = cg/10;
      int ns = (273 - r + d - 1)/d;
      if(s >= ns) continue;                        // uniform across WG
      float acc=0.f;
      const float4* hp = (const float4*)(hLDS + cl*256 + ks*64);
      #pragma unroll
      for(int i=0;i<16;i++){
        float4 h4 = hp[i];
        acc += wv[4*i]*h4.x + wv[4*i+1]*h4.y + wv[4*i+2]*h4.z + wv[4*i+3]*h4.w;
      }
      acc += __shfl_xor(acc,16,64);
      acc += __shfl_xor(acc,32,64);
      if(l<16) zLDS[cl*64 + w*16 + l] = acc;
    }
    __syncthreads();
    // 3. combine: c/h update for (chain, unit) pairs
    for(int i=tid; i<CB*16; i+=256){
      int cl=i>>4, uu=i&15;
      int cg = gg*CB + cl;
      int r = cg/10, j = cg - r*10;
      int ns = (273 - r + d - 1)/d;
      if(s < ns){
        int t = r + s*d;
        const float* zb = Z + (size_t)(t*10+j)*1024 + g*16 + uu;
        float zi = zb[0]   + zLDS[cl*64 +      uu];
        float zf = zb[256] + zLDS[cl*64 + 16 + uu];
        float zg = zb[512] + zLDS[cl*64 + 32 + uu];
        float zo = zb[768] + zLDS[cl*64 + 48 + uu];
        float c = sigf(zf)*cst[i] + sigf(zi)*tanh_(zg);
        float h = sigf(zo)*tanh_(c);
        cst[i]=c;
        Hb[(size_t)((s+1)&1)*60*256 + (size_t)cg*256 + g*16 + uu] = h;
        float o = h;
        if(RES) o += RES[(size_t)(t*10+j)*256 + g*16 + uu];
        Y[(size_t)(t*10+j)*256 + g*16 + uu] = o;
      }
    }
    // 4. cross-WG step barrier (device scope)
    __threadfence();                   // release my h writes past L2
    __syncthreads();
    if(tid==0){
      __hip_atomic_fetch_add(mycnt, 1u, __ATOMIC_RELEASE, __HIP_MEMORY_SCOPE_AGENT);
      u32 tgt = 16u*(u32)(s+1);
      while(__hip_atomic_load(mycnt, __ATOMIC_ACQUIRE, __HIP_MEMORY_SCOPE_AGENT) < tgt){}
    }
    __syncthreads();
    __threadfence();                   // acquire: invalidate before h reads
  }
}

// ---- head: h = tanh(y4 @ linW.T + lb); rnn = h @ scW.T + sb ----
__global__ __launch_bounds__(256) void k_head(const float* __restrict__ Y4,
    const float* __restrict__ LWT,  // [256][256] f32 (linWT: [f][u])
    const float* __restrict__ lb,
    const float* __restrict__ SWT,  // [256][28] f32  (scoreT: [f][o])
    const float* __restrict__ sb,
    float* __restrict__ R){
  __shared__ float v [8][256];
  __shared__ float h2[8][256];
  const int tid = threadIdx.x;
  const int m0 = blockIdx.x*8;
  for(int p=0;p<8;p++){
    int m = m0+p;
    v[p][tid] = (m<NM) ? Y4[m*256+tid] : 0.0f;
  }
  __syncthreads();
  float acc[8];
  float bz = lb[tid];
  #pragma unroll
  for(int p=0;p<8;p++) acc[p]=bz;
  #pragma unroll 4
  for(int f=0; f<256; f++){
    float w = LWT[f*256+tid];
    #pragma unroll
    for(int p=0;p<8;p++) acc[p] += w * v[p][f];
  }
  #pragma unroll
  for(int p=0;p<8;p++) h2[p][tid] = tanh_(acc[p]);
  __syncthreads();
  if(tid < 224){
    int o = tid % 28, p = tid / 28;
    int m = m0 + p;
    if(m < NM){
      float a = sb[o];
      for(int f=0; f<256; f++) a += SWT[f*28+o] * h2[p][f];
      R[m*28+o] = a;
    }
  }
}

// ---- final outputs (f32) ----
// S_ext = concat(S_full[0:307], S_full[300:307]); S_ext[-28:][o] =
//   S_full[286+o] (o<21) else S_full[279+o]
__global__ void k_out(const float* __restrict__ R, const float* __restrict__ ST,
                      const float* __restrict__ lvlT, const float* __restrict__ val,
                      float* __restrict__ out){
  int i = blockIdx.x*256 + threadIdx.x;
  float* o0 = out;                 // prediction_values (245,128,28)
  float* o2 = out + 1756160;       // holdout_prediction (128,28)
  float* o3 = out + 1759744;       // rnn_out (273,128,28)
  float* o4 = out + 2738176;       // hav (128,28)
  float* o5 = out + 2741760;       // hav_norm (128,28)
  if(i < N_O3){
    int o = i % 28;
    int b = (i/28) % 128;
    int t = i/(28*128);
    float vv = R[(t*10 + (b%10))*28 + o];
    o3[i] = vv;
    if(i < N_O0) o0[i] = vv;       // rnn_out[:-OUT], same linear layout
  }
  if(i < 128*28){
    int b = i/28, o = i%28;
    int col = (o < 21) ? (286+o) : (279+o);
    float Sm = ST[col*128 + b];
    float lv = lvlT[299*128 + b];
    float hv = R[(2720 + (b%10))*28 + o] * Sm * lv;
    o2[i] = (hv > 0.0f) ? hv : 0.0f;
    o4[i] = val[i];
    o5[i] = val[i] / Sm / lv;
  }
}

extern "C" void kernel_launch(void* const* d_in, const int* in_sizes, int n_in,
                              void* d_out, int out_size, void* d_ws, size_t ws_size,
                              hipStream_t stream){
  (void)in_sizes; (void)n_in; (void)out_size; (void)ws_size;
  const float* x     = (const float*)d_in[0];
  const float* val   = (const float*)d_in[1];
  const float* alpha = (const float*)d_in[2];
  const float* gamma = (const float*)d_in[3];
  const float* iseas = (const float*)d_in[4];
  const float* cats  = (const float*)d_in[5];
  const float* mp    = (const float*)d_in[6];
  const float* Wih[4]  = {(const float*)d_in[7],  (const float*)d_in[10], (const float*)d_in[13], (const float*)d_in[16]};
  const float* Whh[4]  = {(const float*)d_in[8],  (const float*)d_in[11], (const float*)d_in[14], (const float*)d_in[17]};
  const float* bias[4] = {(const float*)d_in[9],  (const float*)d_in[12], (const float*)d_in[15], (const float*)d_in[18]};
  const float* linW  = (const float*)d_in[19];
  const float* linb  = (const float*)d_in[20];
  const float* scW   = (const float*)d_in[21];
  const float* scb   = (const float*)d_in[22];

  // ---- workspace layout (all f32, every block a multiple of 4 floats) ----
  float* Fw   = (float*)d_ws;
  float* ST   = Fw;                 // 39296
  float* lvlT = ST   + 39296;       // 38400
  float* xT   = lvlT + 38400;       // 38400
  float* win  = xT   + 38400;       // 133776
  float* xz   = win  + 133776;      // 2795520
  float* yA   = xz   + 2795520;     // 698880  (L1 out / L3 out / L4 out)
  float* yB   = yA   + 698880;      // 698880  (L2 out, residual)
  float* rnn  = yB   + 698880;      // 76448
  float* WB   = rnn  + 76448;
  float* wihT[4];
  wihT[0] = WB;                     // 50176
  wihT[1] = wihT[0] + 50176;        // 262144
  wihT[2] = wihT[1] + 262144;
  wihT[3] = wihT[2] + 262144;
  float* linWT = wihT[3] + 262144;  // 65536
  float* scT   = linWT + 65536;     // 7168
  float* Hb    = scT   + 7168;      // 2*60*256 = 30720
  u32*   cnt   = (u32*)(Hb + 30720);// 8 u32

  // ---- weight prep (Wih/lin/score transposes only; Whh used raw) ----
  k_trf<<<(1024*49+255)/256, 256, 0, stream>>>(Wih[0], wihT[0], 1024, 49);
  for(int l=1;l<4;l++)
    k_trf<<<(262144+255)/256, 256, 0, stream>>>(Wih[l], wihT[l], 1024, 256);
  k_trf<<<(65536+255)/256, 256, 0, stream>>>(linW, linWT, 256, 256);
  k_trf<<<(7168+255)/256, 256, 0, stream>>>(scW, scT, 28, 256);
  k_init<<<1, 64, 0, stream>>>(cnt);

  // ---- ES scan + windows ----
  k_xT<<<150, 256, 0, stream>>>(x, xT);
  k_es<<<1, 128, 0, stream>>>(xT, alpha, gamma, iseas, ST, lvlT);
  k_win<<<(NM*49+255)/256, 256, 0, stream>>>(xT, ST, lvlT, cats, mp, win);
  k_wout<<<N_O0/256, 256, 0, stream>>>(xT, ST, lvlT, (float*)d_out + 878080);

  // ---- 4 LSTM layers: batched Wih GEMM + split-unit register scan ----
  const int    dlt[4]  = {1, 2, 2, 6};
  const int    CBs[4]  = {10, 20, 20, 30};   // chains per sync-group
  const int    NGs[4]  = {1, 1, 1, 2};       // sync-groups
  const int    smx[4]  = {273, 137, 137, 46};
  const float* Xin[4]  = {win, yA, yB, yA};
  float*       Yout[4] = {yA, yB, yA, yA};
  const int    Fdim[4] = {49, 256, 256, 256};
  for(int l=0;l<4;l++){
    k_gemm<<<(NM+7)/8, 256, 0, stream>>>(Xin[l], wihT[l], bias[l], xz, Fdim[l]);
    k_scan2<<<NGs[l]*16, 256, 0, stream>>>(xz, Whh[l], Yout[l],
                                           (l==3) ? yB : (const float*)nullptr,
                                           Hb, cnt + l*2, dlt[l], CBs[l], smx[l]);
  }

  // ---- head + outputs ----
  k_head<<<(NM+7)/8, 256, 0, stream>>>(yA, linWT, linb, scT, scb, rnn);
  k_out<<<N_O3/256, 256, 0, stream>>>(rnn, ST, lvlT, val, (float*)d_out);
}